// Round 10
// baseline (2661.994 us; speedup 1.0000x reference)
//
#include <hip/hip_runtime.h>
#include <hip/hip_bf16.h>

#define NSITES 256
#define NM 128        // nup == ndn
#define NMODES 512

typedef unsigned long long u64;
typedef unsigned int u32;

#define REP8(M)    M(0) M(1) M(2) M(3) M(4) M(5) M(6) M(7)
#define REP8P(M,P) M(0,P) M(1,P) M(2,P) M(3,P) M(4,P) M(5,P) M(6,P) M(7,P)

// Integer DPP max step (all-VALU).
template<int CTRL>
__device__ __forceinline__ int dpp_imax(int x) {
  const int y = __builtin_amdgcn_update_dpp(x, x, CTRL, 0xF, 0xF, false);
  return x > y ? x : y;
}
// Wave-wide int max -> uniform scalar (readlane dest is SGPR).
__device__ __forceinline__ int wave_imax_key(int x) {
  x = dpp_imax<0x128>(x);   // row_ror:8
  x = dpp_imax<0x124>(x);   // row_ror:4
  x = dpp_imax<0x122>(x);   // row_ror:2
  x = dpp_imax<0x121>(x);   // row_ror:1
  x = dpp_imax<0x142>(x);   // row_bcast15
  x = dpp_imax<0x143>(x);   // row_bcast31 -> lane 63 has global max
  return __builtin_amdgcn_readlane(x, 63);
}
// Read element p (0..127) of a column stored as (x1: rows 0..63, x2: 64..127).
__device__ __forceinline__ float rl2(float x1, float x2, int p) {
  const int v1 = __builtin_amdgcn_readlane(__float_as_int(x1), p & 63);
  const int v2 = __builtin_amdgcn_readlane(__float_as_int(x2), p & 63);
  return __int_as_float(p < 64 ? v1 : v2);
}
__device__ __forceinline__ float bperm(int byteidx, float v) {
  return __int_as_float(__builtin_amdgcn_ds_bpermute(byteidx, __float_as_int(v)));
}

// One block per BATCH SAMPLE; the block factorizes BOTH spin matrices (A=up,
// B=dn) simultaneously, interleaved in each thread's instruction stream.
// Rationale (R5..R9 evidence): the single-matrix R5 structure is ~60% VALU /
// ~40% latency-stall, and the two LU chains are independent -> interleaving
// fills A's stalls with B's instructions (ILP x2) and halves barriers/matrix.
// Per matrix: R5's proven scheme - thread (tx,ty) owns a[II][JJ] =
// A[II*16+ty][JJ*16+tx]; pivot-retirement (no row swaps); pivot column in
// per-wave regs (c1,c2) -> LDS-free integer-packed DPP argmax; pivot row
// staged to LDS by its owner pre-barrier (fixed-address consume post-barrier;
// R9 showed bpermute broadcast serializes on p); col k+1 advanced in regs,
// col k+2 published to parity-alternating colbuf. ONE barrier per column
// serves both matrices. ALL register indices are preprocessor literals.
__global__ __launch_bounds__(256, 2) void lu_kernel(
    const int* __restrict__ n, const float* __restrict__ phi_up,
    const float* __restrict__ phi_dn, float* __restrict__ ws, int B)
{
  __shared__ int occ[256];            // [0..127] up rows, [128..255] dn rows
  __shared__ int wcnt[8];
  __shared__ float colbufA[2][NM], colbufB[2][NM];
  __shared__ float rowPA[2][NM], rowPB[2][NM];
  __shared__ int ipivA[NM], ipivB[NM];

  const int t = threadIdx.x;
  const int tx = t & 15, ty = t >> 4;
  const int lane = t & 63, wv = t >> 6;
  const int b = blockIdx.x;
  const int* nn = n + b * NMODES;

  // ---- occupied-site lists for both spins (each exactly NM, ascending) ----
  {
    const int v0 = nn[t];            // up sector, site t
    const int v1 = nn[256 + t];      // dn sector, site t
    const u64 m0 = __ballot(v0 != 0), m1 = __ballot(v1 != 0);
    if (lane == 0) { wcnt[wv] = __popcll(m0); wcnt[4 + wv] = __popcll(m1); }
    __syncthreads();
    int off0 = 0, off1 = 128;
    for (int w = 0; w < wv; ++w) { off0 += wcnt[w]; off1 += wcnt[4 + w]; }
    if (v0) occ[off0 + __popcll(m0 & ((1ull << lane) - 1))] = t;
    if (v1) occ[off1 + __popcll(m1 & ((1ull << lane) - 1))] = t;
    __syncthreads();
  }

  // ---- gather both matrices into registers (static indices only) ----
  float aA[8][8], aB[8][8];
#define GATHA(II) { const float* g_ = phi_up + occ[(II)*16 + ty] * NM; \
  aA[II][0]=g_[0*16+tx]; aA[II][1]=g_[1*16+tx]; aA[II][2]=g_[2*16+tx]; aA[II][3]=g_[3*16+tx]; \
  aA[II][4]=g_[4*16+tx]; aA[II][5]=g_[5*16+tx]; aA[II][6]=g_[6*16+tx]; aA[II][7]=g_[7*16+tx]; }
#define GATHB(II) { const float* g_ = phi_dn + occ[128 + (II)*16 + ty] * NM; \
  aB[II][0]=g_[0*16+tx]; aB[II][1]=g_[1*16+tx]; aB[II][2]=g_[2*16+tx]; aB[II][3]=g_[3*16+tx]; \
  aB[II][4]=g_[4*16+tx]; aB[II][5]=g_[5*16+tx]; aB[II][6]=g_[6*16+tx]; aB[II][7]=g_[7*16+tx]; }
  REP8(GATHA)
  REP8(GATHB)
#undef GATHA
#undef GATHB

  // ---- prologue: col 0 -> colbuf*[0], col 1 -> colbuf*[1] ----
#define PUB0(II) { colbufA[0][(II)*16+ty] = aA[II][0]; colbufB[0][(II)*16+ty] = aB[II][0]; }
#define PUB1(II) { colbufA[1][(II)*16+ty] = aA[II][0]; colbufB[1][(II)*16+ty] = aB[II][0]; }
  if (tx == 0) { REP8(PUB0) }
  if (tx == 1) { REP8(PUB1) }
#undef PUB0
#undef PUB1
  __syncthreads();

  float c1A = colbufA[0][lane], c2A = colbufA[0][lane + 64];
  float c1B = colbufB[0][lane], c2B = colbufB[0][lane + 64];
  int r1A = 0, r2A = 0, r1B = 0, r2B = 0;
  float l2sumA = 0.f, l2sumB = 0.f;
  int sbA = 0, sbB = 0;
  const int bidx0 = (ty) << 2;        // bpermute byte-indices for multipliers
  const int bidx1 = (16 + ty) << 2;
  const int bidx2 = (32 + ty) << 2;
  const int bidx3 = (48 + ty) << 2;

#define SRP_CASE(II, ARR) case II: \
  dst_[0*16+tx]=ARR[II][0]; dst_[1*16+tx]=ARR[II][1]; dst_[2*16+tx]=ARR[II][2]; dst_[3*16+tx]=ARR[II][3]; \
  dst_[4*16+tx]=ARR[II][4]; dst_[5*16+tx]=ARR[II][5]; dst_[6*16+tx]=ARR[II][6]; dst_[7*16+tx]=ARR[II][7]; break;

#define DO_AMAX(X) { \
  const int ka1 = r1##X ? 0 : ((__float_as_int(c1##X) & 0x7FFFFF80) | lane); \
  const int ka2 = r2##X ? 0 : ((__float_as_int(c2##X) & 0x7FFFFF80) | (lane + 64)); \
  key##X = wave_imax_key(ka1 > ka2 ? ka1 : ka2); \
}
#define DO_MULT(X) { \
  p##X = key##X & 127; \
  pivv##X = rl2(c1##X, c2##X, p##X); \
  const float rp_ = __builtin_amdgcn_rcpf(pivv##X); \
  r1##X |= (p##X == lane); \
  r2##X |= (p##X == lane + 64); \
  m1##X = r1##X ? 0.f : c1##X * rp_; \
  m2##X = r2##X ? 0.f : c2##X * rp_; \
}
#define DO_STAGE(X) { \
  if (k < NM - 1 && ty == (p##X & 15)) { \
    float* dst_ = &rowP##X[cur][0]; \
    switch (p##X >> 4) { REP8P(SRP_CASE, a##X) } \
  } \
  if (wv == 0) { \
    if (lane == 0) ipiv##X[k] = p##X; \
    l2sum##X += __log2f(fabsf(pivv##X)); \
    sb##X ^= (int)(__float_as_uint(pivv##X) >> 31); \
  } \
}

  for (int k = 0; k < NM; ++k) {
    const int cur = k & 1;
    int keyA, keyB, pA, pB;
    float pivvA, pivvB, m1A, m2A, m1B, m2B;

    // ===== P1 (pre-barrier): both argmax chains (branch-free, overlap) =====
    DO_AMAX(A)
    DO_AMAX(B)
    DO_MULT(A)
    DO_MULT(B)
    DO_STAGE(A)
    DO_STAGE(B)

    __syncthreads();   // single barrier per column, serves both matrices

    // ===== P2 (post-barrier): dual rank-1 update =====
    if (k < NM - 1) {
      // next pivot columns (prefetch; latency hides under bpermutes)
      const float dA1 = colbufA[cur ^ 1][lane], dA2 = colbufA[cur ^ 1][lane + 64];
      const float dB1 = colbufB[cur ^ 1][lane], dB2 = colbufB[cur ^ 1][lane + 64];

      // multipliers for my 8 rows, both matrices (independent DS ops)
      float mIA[8], mIB[8];
      mIA[0] = bperm(bidx0, m1A); mIA[1] = bperm(bidx1, m1A);
      mIA[2] = bperm(bidx2, m1A); mIA[3] = bperm(bidx3, m1A);
      mIA[4] = bperm(bidx0, m2A); mIA[5] = bperm(bidx1, m2A);
      mIA[6] = bperm(bidx2, m2A); mIA[7] = bperm(bidx3, m2A);
      mIB[0] = bperm(bidx0, m1B); mIB[1] = bperm(bidx1, m1B);
      mIB[2] = bperm(bidx2, m1B); mIB[3] = bperm(bidx3, m1B);
      mIB[4] = bperm(bidx0, m2B); mIB[5] = bperm(bidx1, m2B);
      mIB[6] = bperm(bidx2, m2B); mIB[7] = bperm(bidx3, m2B);

      // fused rank-1 updates of columns >= k+1 (block-trimmed, one switch)
      const float* rPA_ = &rowPA[cur][0];
      const float* rPB_ = &rowPB[cur][0];
      float prA[8], prB[8];
      const int T = (k + 1) >> 4;
#define PRE2(JJ, KB) if ((JJ) >= (KB)) { prA[JJ] = rPA_[(JJ)*16 + tx]; prB[JJ] = rPB_[(JJ)*16 + tx]; }
#define UPD2(II, KB) { \
  if (0 >= (KB)) { aA[II][0]=fmaf(-mIA[II],prA[0],aA[II][0]); aB[II][0]=fmaf(-mIB[II],prB[0],aB[II][0]); } \
  if (1 >= (KB)) { aA[II][1]=fmaf(-mIA[II],prA[1],aA[II][1]); aB[II][1]=fmaf(-mIB[II],prB[1],aB[II][1]); } \
  if (2 >= (KB)) { aA[II][2]=fmaf(-mIA[II],prA[2],aA[II][2]); aB[II][2]=fmaf(-mIB[II],prB[2],aB[II][2]); } \
  if (3 >= (KB)) { aA[II][3]=fmaf(-mIA[II],prA[3],aA[II][3]); aB[II][3]=fmaf(-mIB[II],prB[3],aB[II][3]); } \
  if (4 >= (KB)) { aA[II][4]=fmaf(-mIA[II],prA[4],aA[II][4]); aB[II][4]=fmaf(-mIB[II],prB[4],aB[II][4]); } \
  if (5 >= (KB)) { aA[II][5]=fmaf(-mIA[II],prA[5],aA[II][5]); aB[II][5]=fmaf(-mIB[II],prB[5],aB[II][5]); } \
  if (6 >= (KB)) { aA[II][6]=fmaf(-mIA[II],prA[6],aA[II][6]); aB[II][6]=fmaf(-mIB[II],prB[6],aB[II][6]); } \
  if (7 >= (KB)) { aA[II][7]=fmaf(-mIA[II],prA[7],aA[II][7]); aB[II][7]=fmaf(-mIB[II],prB[7],aB[II][7]); } }
#define LUCASE(KB) case KB: { REP8P(PRE2, KB) REP8P(UPD2, KB) } break;
      switch (T) {
        REP8(LUCASE)
      }
#undef LUCASE
#undef UPD2
#undef PRE2

      // advance pivot-column windows (col k+1 -> through k, in regs)
      const float udA = rl2(dA1, dA2, pA);
      c1A = fmaf(-m1A, udA, dA1);
      c2A = fmaf(-m2A, udA, dA2);
      const float udB = rl2(dB1, dB2, pB);
      c1B = fmaf(-m1B, udB, dB1);
      c2B = fmaf(-m2B, udB, dB2);

      // publish col k+2 (through k) into colbuf*[cur] (one fused switch)
      if (k < NM - 2) {
        const int cn = k + 2;
        if (tx == (cn & 15)) {
          float* cbA_ = &colbufA[cur][0];
          float* cbB_ = &colbufB[cur][0];
          switch (cn >> 4) {
#define PUBJ(JJ) case JJ: \
  cbA_[0*16+ty]=aA[0][JJ]; cbA_[1*16+ty]=aA[1][JJ]; cbA_[2*16+ty]=aA[2][JJ]; cbA_[3*16+ty]=aA[3][JJ]; \
  cbA_[4*16+ty]=aA[4][JJ]; cbA_[5*16+ty]=aA[5][JJ]; cbA_[6*16+ty]=aA[6][JJ]; cbA_[7*16+ty]=aA[7][JJ]; \
  cbB_[0*16+ty]=aB[0][JJ]; cbB_[1*16+ty]=aB[1][JJ]; cbB_[2*16+ty]=aB[2][JJ]; cbB_[3*16+ty]=aB[3][JJ]; \
  cbB_[4*16+ty]=aB[4][JJ]; cbB_[5*16+ty]=aB[5][JJ]; cbB_[6*16+ty]=aB[6][JJ]; cbB_[7*16+ty]=aB[7][JJ]; break;
            REP8(PUBJ)
#undef PUBJ
          }
        }
      }
    }
  }
#undef DO_STAGE
#undef DO_MULT
#undef DO_AMAX
#undef SRP_CASE

  // ---- permutation parities (waves 0-1: A, waves 2-3: B) ----
  __syncthreads();
  {
    const int* ip = (t < 128) ? ipivA : ipivB;
    const int tt = t & 127;
    const int my = ip[tt];
    int inv = 0;
    for (int l = tt + 1; l < NM; ++l) inv += (my > ip[l]) ? 1 : 0;
    const u64 bal = __ballot(inv & 1);
    if (lane == 0) wcnt[wv] = __popcll(bal);
  }
  __syncthreads();

  if (t == 0) {
    const int parA = (wcnt[0] + wcnt[1]) & 1;
    const int parB = (wcnt[2] + wcnt[3]) & 1;
    const float LN2 = 0.6931471805599453f;
    ws[B + 0 * B + b] = l2sumA * LN2;                  // logabs up
    ws[B + 1 * B + b] = l2sumB * LN2;                  // logabs dn
    ws[3 * B + 0 * B + b] = ((sbA ^ parA) & 1) ? -1.f : 1.f;  // sign up
    ws[3 * B + 1 * B + b] = ((sbB ^ parB) & 1) ? -1.f : 1.f;  // sign dn
  }
}

// One block per batch: log_j = -0.5 * sum_{i occ} sum_c v[i][c] * nf[c]
__global__ __launch_bounds__(256) void jastrow_kernel(
    const int* __restrict__ n, const float* __restrict__ v,
    float* __restrict__ ws, int B)
{
  __shared__ int occ[256];
  __shared__ float nf[NMODES];
  __shared__ int wcnt[8];
  __shared__ float red[256];
  const int t = threadIdx.x, b = blockIdx.x;
  const int lane = t & 63, wv = t >> 6;
  const int* nn = n + b * NMODES;
  int v0 = nn[t], v1 = nn[256 + t];
  nf[t] = (float)v0;
  nf[256 + t] = (float)v1;
  u64 m0 = __ballot(v0 != 0), m1 = __ballot(v1 != 0);
  if (lane == 0) { wcnt[wv] = __popcll(m0); wcnt[4 + wv] = __popcll(m1); }
  __syncthreads();
  int off0 = 0;
  for (int w = 0; w < wv; ++w) off0 += wcnt[w];
  int base1 = wcnt[0] + wcnt[1] + wcnt[2] + wcnt[3];
  int off1 = base1;
  for (int w = 0; w < wv; ++w) off1 += wcnt[4 + w];
  if (v0) occ[off0 + __popcll(m0 & ((1ull << lane) - 1))] = t;
  if (v1) occ[off1 + __popcll(m1 & ((1ull << lane) - 1))] = 256 + t;
  __syncthreads();

  float acc = 0.f;
  for (int r = wv * 64; r < wv * 64 + 64; ++r) {
    const float* row = v + occ[r] * NMODES;   // occ[r] wave-uniform -> broadcast
#pragma unroll
    for (int cc = 0; cc < 8; ++cc) {
      int c = cc * 64 + lane;                 // coalesced 256B per iter
      acc += row[c] * nf[c];
    }
  }
  red[t] = acc;
  __syncthreads();
  for (int s = 128; s >= 1; s >>= 1) {
    if (t < s) red[t] += red[t + s];
    __syncthreads();
  }
  if (t == 0) ws[b] = -0.5f * red[0];
}

__global__ void finalize_kernel(const float* __restrict__ ws,
                                float* __restrict__ out, int B)
{
  int b = blockIdx.x * 256 + threadIdx.x;
  if (b < B) {
    float lj = ws[b];
    float la_u = ws[B + b], la_d = ws[2 * B + b];
    float s_u = ws[3 * B + b], s_d = ws[4 * B + b];
    out[b] = s_u * s_d;
    out[B + b] = lj + la_u + la_d;
  }
}

extern "C" void kernel_launch(void* const* d_in, const int* in_sizes, int n_in,
                              void* d_out, int out_size, void* d_ws, size_t ws_size,
                              hipStream_t stream) {
  const int* n = (const int*)d_in[0];
  const float* phi_up = (const float*)d_in[1];
  const float* phi_dn = (const float*)d_in[2];
  const float* v = (const float*)d_in[3];
  float* out = (float*)d_out;
  float* ws = (float*)d_ws;
  const int B = in_sizes[0] / NMODES;  // 4096

  jastrow_kernel<<<B, 256, 0, stream>>>(n, v, ws, B);
  lu_kernel<<<B, 256, 0, stream>>>(n, phi_up, phi_dn, ws, B);
  finalize_kernel<<<(B + 255) / 256, 256, 0, stream>>>(ws, out, B);
}